// Round 14
// baseline (208.242 us; speedup 1.0000x reference)
//
#include <hip/hip_runtime.h>
#include <hip/hip_bf16.h>
#include <cstdint>
#include <cmath>

#define N_TOK 8192
#define CDIM  768
#define HDIM  3072
#define NEXP  8
#define NBLK  256     // router/gather blocks, 32 tokens each

typedef __bf16 bf16;
typedef __bf16 bf16x4 __attribute__((ext_vector_type(4)));
typedef __bf16 bf16x8 __attribute__((ext_vector_type(8)));
typedef float  f32x4  __attribute__((ext_vector_type(4)));

// ws byte offsets
#define WS_BE      0u          // 8192 int
#define WS_TPROB   32768u      // 8192 f32
#define WS_CNTB    65536u      // 256*8 int
#define WS_IMPB    73728u      // 256*8 f32
#define WS_BASEB   81920u      // 256*8 int
#define WS_CNT     90112u      // 8 int
#define WS_OFF     90176u      // 9 int
#define WS_TOKMAP  98304u      // 9216 int
#define WS_TPG     137216u     // 9216 f32  -> ends 174080
#define WS_XGT     (1u<<20)    // 72*12*16384 = 14,155,776
#define WS_W1T     (16u<<20)   // 37,748,736 -> ends 54,525,952
#define WS_HBUF    (56u<<20)   // 72*48*16384 = 56,623,104 -> ends 115,343,360
#define WS_W2T     (1u<<20)    // aliases XGT/W1T, written after ffn1

__device__ __forceinline__ void load16_lds(const void* g, void* l) {
  __builtin_amdgcn_global_load_lds(
      (const __attribute__((address_space(1))) void*)g,
      (__attribute__((address_space(3))) void*)l, 16, 0, 0);
}

// ---------------------------------------------------------------------------
// Router: 256 blocks x 32 tokens, wave-per-token (8 tokens/wave).
// ---------------------------------------------------------------------------
__global__ __launch_bounds__(256) void router3(
    const float* __restrict__ x, const float* __restrict__ Wr,
    float* __restrict__ tprob, int* __restrict__ be_out,
    int* __restrict__ cnt_blk, float* __restrict__ imp_blk)
{
  const int tid = threadIdx.x, lane = tid & 63, wv = tid >> 6;
  const int b = blockIdx.x;
  __shared__ int cnt_l[NEXP];
  __shared__ float imp_l[4][NEXP];
  if (tid < NEXP) cnt_l[tid] = 0;

  float wreg[12][8];
  #pragma unroll
  for (int j = 0; j < 3; ++j)
    #pragma unroll
    for (int q = 0; q < 4; ++q) {
      const float4* p = (const float4*)(Wr + (size_t)(j * 256 + lane * 4 + q) * 8);
      float4 lo = p[0], hi = p[1];
      wreg[j*4+q][0] = lo.x; wreg[j*4+q][1] = lo.y;
      wreg[j*4+q][2] = lo.z; wreg[j*4+q][3] = lo.w;
      wreg[j*4+q][4] = hi.x; wreg[j*4+q][5] = hi.y;
      wreg[j*4+q][6] = hi.z; wreg[j*4+q][7] = hi.w;
    }

  float impacc[NEXP];
  #pragma unroll
  for (int e = 0; e < NEXP; ++e) impacc[e] = 0.0f;
  __syncthreads();

  #pragma unroll 1
  for (int t = 0; t < 8; ++t) {
    const int tok = b * 32 + wv * 8 + t;
    float4 xv[3];
    #pragma unroll
    for (int j = 0; j < 3; ++j)
      xv[j] = *(const float4*)(x + (size_t)tok * CDIM + j * 256 + lane * 4);

    float acc[NEXP];
    #pragma unroll
    for (int e = 0; e < NEXP; ++e) acc[e] = 0.0f;
    #pragma unroll
    for (int j = 0; j < 3; ++j) {
      const float xa[4] = {xv[j].x, xv[j].y, xv[j].z, xv[j].w};
      #pragma unroll
      for (int q = 0; q < 4; ++q)
        #pragma unroll
        for (int e = 0; e < NEXP; ++e)
          acc[e] = fmaf(xa[q], wreg[j*4+q][e], acc[e]);
    }
    #pragma unroll
    for (int e = 0; e < NEXP; ++e) {
      float v = acc[e];
      v += __shfl_xor(v, 1);  v += __shfl_xor(v, 2);  v += __shfl_xor(v, 4);
      v += __shfl_xor(v, 8);  v += __shfl_xor(v, 16); v += __shfl_xor(v, 32);
      acc[e] = v;
    }
    float m = acc[0]; int be = 0;
    #pragma unroll
    for (int e = 1; e < NEXP; ++e) if (acc[e] > m) { m = acc[e]; be = e; }
    float pr[NEXP]; float s = 0.0f;
    #pragma unroll
    for (int e = 0; e < NEXP; ++e) { pr[e] = __expf(acc[e] - m); s += pr[e]; }
    const float inv = 1.0f / s;
    #pragma unroll
    for (int e = 0; e < NEXP; ++e) impacc[e] += pr[e] * inv;
    if (lane == 0) {
      tprob[tok]  = pr[be] * inv;
      be_out[tok] = be;
      atomicAdd(&cnt_l[be], 1);
    }
  }

  if (lane == 0) {
    #pragma unroll
    for (int e = 0; e < NEXP; ++e) imp_l[wv][e] = impacc[e];
  }
  __syncthreads();
  if (tid < NEXP) {
    cnt_blk[b * NEXP + tid] = cnt_l[tid];
    imp_blk[b * NEXP + tid] =
        imp_l[0][tid] + imp_l[1][tid] + imp_l[2][tid] + imp_l[3][tid];
  }
}

// ---------------------------------------------------------------------------
// Scan: per-expert exclusive scan over 256 blocks, 128-aligned offsets,
// counts, importance, aux loss, pad tokmap = -1. No atomics.
// ---------------------------------------------------------------------------
__global__ __launch_bounds__(256) void scan_kernel(
    const int* __restrict__ cnt_blk, const float* __restrict__ imp_blk,
    int* __restrict__ counts, int* __restrict__ off,
    int* __restrict__ base_blk, float* __restrict__ out_aux,
    int* __restrict__ tokmap)
{
  const int tid = threadIdx.x, lane = tid & 63, wv = tid >> 6;
  __shared__ int   wsum[NEXP][4];
  __shared__ float wimp[NEXP][4];
  __shared__ int   off_s[9];
  __shared__ int   cnt_s[NEXP];

  int pref[NEXP];
  #pragma unroll
  for (int e = 0; e < NEXP; ++e) {
    int v = cnt_blk[tid * NEXP + e];
    int inc = v;
    #pragma unroll
    for (int o = 1; o < 64; o <<= 1) {
      int n = __shfl_up(inc, o);
      if (lane >= o) inc += n;
    }
    if (lane == 63) wsum[e][wv] = inc;
    pref[e] = inc - v;

    float f = imp_blk[tid * NEXP + e];
    f += __shfl_xor(f, 1);  f += __shfl_xor(f, 2);  f += __shfl_xor(f, 4);
    f += __shfl_xor(f, 8);  f += __shfl_xor(f, 16); f += __shfl_xor(f, 32);
    if (lane == 0) wimp[e][wv] = f;
  }
  __syncthreads();
  if (tid == 0) {
    int o = 0; float aux = 0.0f;
    #pragma unroll
    for (int e = 0; e < NEXP; ++e) {
      int tot = wsum[e][0] + wsum[e][1] + wsum[e][2] + wsum[e][3];
      float im = wimp[e][0] + wimp[e][1] + wimp[e][2] + wimp[e][3];
      counts[e] = tot;
      cnt_s[e] = tot;
      aux += im * (float)tot;
      off_s[e] = o;
      o += (tot + 127) & ~127;
    }
    off_s[8] = o;
    out_aux[0] = (float)NEXP * aux / ((float)N_TOK * (float)N_TOK);
    for (int i = 0; i < 9; ++i) off[i] = off_s[i];
  }
  __syncthreads();
  #pragma unroll
  for (int e = 0; e < NEXP; ++e) {
    int wofs = 0;
    #pragma unroll
    for (int w = 0; w < 4; ++w) if (w < wv) wofs += wsum[e][w];
    base_blk[tid * NEXP + e] = off_s[e] + wofs + pref[e];
  }
  #pragma unroll 1
  for (int e = 0; e < NEXP; ++e) {
    int p0 = off_s[e] + cnt_s[e], p1 = off_s[e + 1];
    for (int i = p0 + tid; i < p1; i += 256) tokmap[i] = -1;
  }
}

// ---------------------------------------------------------------------------
// Gather: pack routed token rows into xgT [tile128][kc:12][128][64] swizzled.
// ---------------------------------------------------------------------------
__global__ __launch_bounds__(256) void gather2(
    const float* __restrict__ x, const float* __restrict__ tprob,
    const int* __restrict__ be, const int* __restrict__ base_blk,
    bf16* __restrict__ xgT, int* __restrict__ tokmap, float* __restrict__ tpg)
{
  const int tid = threadIdx.x, lane = tid & 63, wv = tid >> 6;
  const int b = blockIdx.x;
  __shared__ int slot_l[32];

  if (wv == 0) {
    const int t = lane;
    const int bet = (t < 32) ? be[b * 32 + t] : -1;
    int slot = -1;
    #pragma unroll
    for (int e = 0; e < NEXP; ++e) {
      unsigned long long msk = __ballot(bet == e);
      if (bet == e) {
        int rank = __popcll(msk & ((1ull << lane) - 1ull));
        slot = base_blk[b * NEXP + e] + rank;
      }
    }
    if (t < 32) {
      slot_l[t] = slot;
      const int tok = b * 32 + t;
      tokmap[slot] = tok;
      tpg[slot] = tprob[tok];
    }
  }
  __syncthreads();

  #pragma unroll 1
  for (int t8 = 0; t8 < 8; ++t8) {
    const int t = wv * 8 + t8;
    const int slot = slot_l[t];
    const int tok = b * 32 + t;
    const int tile = slot >> 7, r = slot & 127;
    #pragma unroll
    for (int j = 0; j < 3; ++j) {
      const int col = j * 256 + lane * 4;
      const int kc = col >> 6, cw = col & 63;
      float4 v = *(const float4*)(x + (size_t)tok * CDIM + col);
      bf16x4 o;
      o[0] = (bf16)v.x; o[1] = (bf16)v.y; o[2] = (bf16)v.z; o[3] = (bf16)v.w;
      char* dst = (char*)xgT + (((size_t)tile * 12 + kc) * 128 + r) * 128
                  + ((cw * 2) ^ ((r & 7) << 4));
      *(bf16x4*)dst = o;
    }
  }
}

// ---------------------------------------------------------------------------
// W [E][R][S] fp32 -> tiled bf16 [E][S/64][R/64][64][64], swizzled rows.
// ---------------------------------------------------------------------------
__global__ __launch_bounds__(256) void transpose_w(
    const float* __restrict__ W, bf16* __restrict__ WT, int R, int S)
{
  __shared__ float t[64][65];
  const int r0 = blockIdx.x * 64, s0 = blockIdx.y * 64, e = blockIdx.z;
  const float* We = W + (size_t)e * R * S;
  const int NT = S >> 6, NK = R >> 6;
  char* outT = (char*)WT + (((size_t)e * NT + (s0 >> 6)) * NK + (r0 >> 6)) * 8192;
  const int tid = threadIdx.x, lr = tid >> 4, lc4 = tid & 15;

  #pragma unroll
  for (int j = 0; j < 4; ++j) {
    int r = lr + j * 16;
    float4 v = *(const float4*)(We + (size_t)(r0 + r) * S + s0 + lc4 * 4);
    t[r][lc4 * 4 + 0] = v.x; t[r][lc4 * 4 + 1] = v.y;
    t[r][lc4 * 4 + 2] = v.z; t[r][lc4 * 4 + 3] = v.w;
  }
  __syncthreads();
  #pragma unroll
  for (int j = 0; j < 4; ++j) {
    int sI = lr + j * 16;
    bf16x4 o;
    #pragma unroll
    for (int q = 0; q < 4; ++q) o[q] = (bf16)t[lc4 * 4 + q][sI];
    *(bf16x4*)(outT + sI * 128 + ((lc4 * 8) ^ ((sI & 7) << 4))) = o;
  }
}

// ---------------------------------------------------------------------------
// Grouped GEMM, B-direct variant: BM=128, BN=128, BK=64, 4 waves (2x2).
// A: LDS double-buffer (2x16 KB = 32 KB), global_load_lds DMA, depth-2.
// B: DIRECT global->VGPR loads (pre-swizzled tiled layout => each lane's
//    16-B fragment is at a computable address), register double-buffered
//    via 2x-unrolled loop with named sets (no LDS write/read for B at all).
// Per iter: barrier; ds_read A(cur); lgkm0+sb; barrier; loadB(k+1)->regs;
//   stageA(k+2) into freed buf; MFMA half0; vmcnt(4) [drains A(k+1)+B(k+1),
//   A(k+2) stays in flight]; MFMA half1.
// ---------------------------------------------------------------------------
template<int NKC, int NCHN, bool GELU>
__global__ __launch_bounds__(256, 2) void ffn_d(
    const bf16* __restrict__ Abuf, const bf16* __restrict__ Wt,
    const float* __restrict__ bias, const int* __restrict__ off,
    const int* __restrict__ tokmap, const float* __restrict__ tpg,
    bf16* __restrict__ hbufT, float* __restrict__ y)
{
  const int bid = blockIdx.x + blockIdx.y * 72;
  const int c  = bid & 7;
  const int r2 = bid >> 3;
  const int bx = c * 9 + (r2 % 9);
  const int by = r2 / 9;

  const int ptot = off[8];
  const int m0 = bx * 128;
  if (m0 >= ptot) return;
  int e = 0;
  #pragma unroll
  for (int q = 0; q < 7; ++q) if (m0 >= off[q + 1]) e = q + 1;

  const int tid = threadIdx.x, lane = tid & 63, wv = tid >> 6;
  const int wr = (wv >> 1) * 64;
  const int wc = (wv & 1) * 64;

  __shared__ __attribute__((aligned(1024))) char smem[32768];
  // A buf0 @0 (16K), A buf1 @16K

  const char* aBase = (const char*)Abuf + (size_t)bx * NKC * 16384;
  const int ub = by * 2 + (wv & 1);              // this wave's 64-col unit
  const char* bUnit = (const char*)Wt + (((size_t)e * NCHN + ub) * NKC) * 8192;

  auto stageA = [&](int buf, int kc) {
    const char* aS = aBase + (size_t)kc * 16384 + wv * 4096 + lane * 16;
    char* ab = smem + buf * 16384;
    #pragma unroll
    for (int i = 0; i < 4; ++i)
      load16_lds(aS + i * 1024, ab + wv * 4096 + i * 1024);
  };

  // hoisted lane-constant offsets
  int aoff[2][4], bvo[2][4];
  #pragma unroll
  for (int kk = 0; kk < 2; ++kk)
    #pragma unroll
    for (int f = 0; f < 4; ++f) {
      int rowA = wr + f * 16 + (lane & 15);
      int ba   = rowA * 128 + kk * 64 + (lane >> 4) * 16;
      aoff[kk][f] = ba ^ ((rowA & 7) << 4);
      int rowB = f * 16 + (lane & 15);           // 0..63 within unit
      bvo[kk][f] = rowB * 128 + ((kk * 64 + (lane >> 4) * 16) ^ ((rowB & 7) << 4));
    }

  f32x4 acc[4][4];
  #pragma unroll
  for (int i = 0; i < 4; ++i)
    #pragma unroll
    for (int j = 0; j < 4; ++j)
      #pragma unroll
      for (int q = 0; q < 4; ++q) acc[i][j][q] = 0.0f;

  bf16x8 bA[2][4], bB[2][4];   // named double sets (rule #20: no runtime idx)

  // prologue: B(0) [8 loads, oldest], A(0) [4 DMA], A(1) [4 DMA, newest]
  {
    #pragma unroll
    for (int kk = 0; kk < 2; ++kk)
      #pragma unroll
      for (int f = 0; f < 4; ++f)
        bA[kk][f] = *(const bf16x8*)(bUnit + bvo[kk][f]);
  }
  __builtin_amdgcn_sched_barrier(0);
  stageA(0, 0);
  stageA(1, 1);
  asm volatile("s_waitcnt vmcnt(4)" ::: "memory");   // B(0)+A(0) done, A(1) flies

  auto body = [&](int j, bf16x8 (&bCur)[2][4], bf16x8 (&bNxt)[2][4]) {
    const int cur = j & 1;
    __builtin_amdgcn_s_barrier();          // A(j) resident in all waves
    const char* A = smem + cur * 16384;
    bf16x8 af[2][4];
    #pragma unroll
    for (int kk = 0; kk < 2; ++kk)
      #pragma unroll
      for (int f = 0; f < 4; ++f)
        af[kk][f] = *(const bf16x8*)(A + aoff[kk][f]);
    asm volatile("s_waitcnt lgkmcnt(0)" ::: "memory");
    __builtin_amdgcn_sched_barrier(0);     // rule #18
    __builtin_amdgcn_s_barrier();          // all waves done reading buf(cur)
    if (j + 1 < NKC) {                     // B(j+1) first (drained at bottom)
      const char* p = bUnit + (size_t)(j + 1) * 8192;
      #pragma unroll
      for (int kk = 0; kk < 2; ++kk)
        #pragma unroll
        for (int f = 0; f < 4; ++f)
          bNxt[kk][f] = *(const bf16x8*)(p + bvo[kk][f]);
    }
    __builtin_amdgcn_sched_barrier(0);
    if (j + 2 < NKC) stageA(cur, j + 2);   // A(j+2) last (stays in flight)
    __builtin_amdgcn_sched_barrier(0);

    __builtin_amdgcn_s_setprio(1);
    #pragma unroll
    for (int fm = 0; fm < 4; ++fm)
      #pragma unroll
      for (int fn = 0; fn < 4; ++fn)
        acc[fm][fn] = __builtin_amdgcn_mfma_f32_16x16x32_bf16(
            af[0][fm], bCur[0][fn], acc[fm][fn], 0, 0, 0);
    __builtin_amdgcn_s_setprio(0);

    if (j + 1 < NKC) {
      __builtin_amdgcn_sched_barrier(0);
      if (j + 2 < NKC)
        asm volatile("s_waitcnt vmcnt(4)" ::: "memory"); // A(j+1)+B(j+1) done
      else
        asm volatile("s_waitcnt vmcnt(0)" ::: "memory"); // tail drain
      __builtin_amdgcn_sched_barrier(0);
    }

    __builtin_amdgcn_s_setprio(1);
    #pragma unroll
    for (int fm = 0; fm < 4; ++fm)
      #pragma unroll
      for (int fn = 0; fn < 4; ++fn)
        acc[fm][fn] = __builtin_amdgcn_mfma_f32_16x16x32_bf16(
            af[1][fm], bCur[1][fn], acc[fm][fn], 0, 0, 0);
    __builtin_amdgcn_s_setprio(0);
  };

  #pragma unroll 1
  for (int j2 = 0; j2 < NKC; j2 += 2) {    // NKC is even (12 / 48)
    body(j2,     bA, bB);
    body(j2 + 1, bB, bA);
  }
  __syncthreads();     // epilogue reuses smem

  const int g = lane >> 4, ci = lane & 15;
  float bv[4];
  #pragma unroll
  for (int fn = 0; fn < 4; ++fn)
    bv[fn] = bias[e * (NCHN * 64) + by * 128 + wc + fn * 16 + ci];

  if (GELU) {
    // bias + tanh-GELU -> swizzled bf16 C tile (exactly 32 KB) -> linear copy
    #pragma unroll
    for (int fm = 0; fm < 4; ++fm)
      #pragma unroll
      for (int fn = 0; fn < 4; ++fn)
        #pragma unroll
        for (int rg = 0; rg < 4; ++rg) {
          int row = wr + fm * 16 + g * 4 + rg;
          int col = wc + fn * 16 + ci;
          float v = acc[fm][fn][rg] + bv[fn];
          float t3 = v + 0.044715f * v * v * v;
          float gel = v / (1.0f + __expf(-1.5957691216f * t3));
          int chunk = col >> 6, cw = col & 63;
          int byte = chunk * 16384 + row * 128 + ((cw * 2) ^ ((row & 7) << 4));
          *(bf16*)(smem + byte) = (bf16)gel;
        }
    __syncthreads();
    char* hdst = (char*)hbufT + ((size_t)bx * 48 + by * 2) * 16384;
    #pragma unroll
    for (int i = 0; i < 8; ++i) {
      int bo = (i * 256 + tid) * 16;
      *(f32x4*)(hdst + bo) = *(const f32x4*)(smem + bo);
    }
  } else {
    // bias + tprob -> two [128][64]-f32 col-halves (32 KB each) -> scatter
    float tp[4][4];
    #pragma unroll
    for (int fm = 0; fm < 4; ++fm)
      #pragma unroll
      for (int rg = 0; rg < 4; ++rg)
        tp[fm][rg] = tpg[m0 + wr + fm * 16 + g * 4 + rg];
    float* smemf = (float*)smem;
    #pragma unroll
    for (int h = 0; h < 2; ++h) {
      if ((wv & 1) == h) {
        #pragma unroll
        for (int fm = 0; fm < 4; ++fm)
          #pragma unroll
          for (int fn = 0; fn < 4; ++fn)
            #pragma unroll
            for (int rg = 0; rg < 4; ++rg) {
              int row = wr + fm * 16 + g * 4 + rg;
              int cl  = fn * 16 + ci;                // 0..63 within half
              smemf[row * 64 + cl] = (acc[fm][fn][rg] + bv[fn]) * tp[fm][rg];
            }
      }
      __syncthreads();
      // full half: 128 rows x 16 f32x4 = 2048 vec4s, 8 per thread
      #pragma unroll
      for (int it = 0; it < 8; ++it) {
        int lin = it * 256 + tid;
        int row = lin >> 4;
        int c4  = lin & 15;
        int tokr = tokmap[m0 + row];
        f32x4 v = *(const f32x4*)(smemf + row * 64 + c4 * 4);
        if (tokr >= 0)
          *(f32x4*)(y + (size_t)tokr * CDIM + by * 128 + h * 64 + c4 * 4) = v;
      }
      __syncthreads();
    }
  }
}

// ---------------------------------------------------------------------------
extern "C" void kernel_launch(void* const* d_in, const int* in_sizes, int n_in,
                              void* d_out, int out_size, void* d_ws, size_t ws_size,
                              hipStream_t stream)
{
  const float* x  = (const float*)d_in[0];
  const float* Wr = (const float*)d_in[1];
  const float* W1 = (const float*)d_in[2];
  const float* b1 = (const float*)d_in[3];
  const float* W2 = (const float*)d_in[4];
  const float* b2 = (const float*)d_in[5];
  float* out = (float*)d_out;

  char* ws = (char*)d_ws;
  int*   be         = (int*)(ws + WS_BE);
  float* tprob      = (float*)(ws + WS_TPROB);
  int*   cnt_blk    = (int*)(ws + WS_CNTB);
  float* imp_blk    = (float*)(ws + WS_IMPB);
  int*   base_blk   = (int*)(ws + WS_BASEB);
  int*   counts     = (int*)(ws + WS_CNT);
  int*   off        = (int*)(ws + WS_OFF);
  int*   tokmap     = (int*)(ws + WS_TOKMAP);
  float* tpg        = (float*)(ws + WS_TPG);
  bf16*  xgT        = (bf16*)(ws + WS_XGT);
  bf16*  w1tT       = (bf16*)(ws + WS_W1T);
  bf16*  hbufT      = (bf16*)(ws + WS_HBUF);
  bf16*  w2tT       = (bf16*)(ws + WS_W2T);   // written after ffn1

  router3<<<dim3(NBLK), 256, 0, stream>>>(x, Wr, tprob, be, cnt_blk, imp_blk);
  scan_kernel<<<dim3(1), 256, 0, stream>>>(cnt_blk, imp_blk, counts, off,
                                           base_blk, out + (size_t)N_TOK * CDIM,
                                           tokmap);
  gather2<<<dim3(NBLK), 256, 0, stream>>>(x, tprob, be, base_blk,
                                          xgT, tokmap, tpg);
  transpose_w<<<dim3(CDIM / 64, HDIM / 64, NEXP), 256, 0, stream>>>(
      W1, w1tT, CDIM, HDIM);
  ffn_d<12, 48, true><<<dim3(72, 24), 256, 0, stream>>>(
      xgT, w1tT, b1, off, nullptr, nullptr, hbufT, nullptr);
  transpose_w<<<dim3(HDIM / 64, CDIM / 64, NEXP), 256, 0, stream>>>(
      W2, w2tT, HDIM, CDIM);
  ffn_d<48, 12, false><<<dim3(72, 6), 256, 0, stream>>>(
      hbufT, w2tT, b2, off, tokmap, tpg, nullptr, out);
}

// Round 15
// 183.623 us; speedup vs baseline: 1.1341x; 1.1341x over previous
//
#include <hip/hip_runtime.h>
#include <hip/hip_bf16.h>
#include <cstdint>
#include <cmath>

#define N_TOK 8192
#define CDIM  768
#define HDIM  3072
#define NEXP  8
#define NBLK  256     // router/gather blocks, 32 tokens each

typedef __bf16 bf16;
typedef __bf16 bf16x4 __attribute__((ext_vector_type(4)));
typedef __bf16 bf16x8 __attribute__((ext_vector_type(8)));
typedef float  f32x4  __attribute__((ext_vector_type(4)));

// ws byte offsets
#define WS_BE      0u          // 8192 int
#define WS_TPROB   32768u      // 8192 f32
#define WS_CNTB    65536u      // 256*8 int
#define WS_IMPB    73728u      // 256*8 f32
#define WS_BASEB   81920u      // 256*8 int
#define WS_CNT     90112u      // 8 int
#define WS_OFF     90176u      // 9 int
#define WS_TOKMAP  98304u      // 9216 int
#define WS_TPG     137216u     // 9216 f32  -> ends 174080
#define WS_XGT     (1u<<20)    // 72*12*16384 = 14,155,776
#define WS_W1T     (16u<<20)   // 37,748,736 -> ends 54,525,952
#define WS_HBUF    (56u<<20)   // 72*48*16384 = 56,623,104 -> ends 115,343,360
#define WS_W2T     (1u<<20)    // aliases XGT/W1T, written after ffn1

__device__ __forceinline__ void load16_lds(const void* g, void* l) {
  __builtin_amdgcn_global_load_lds(
      (const __attribute__((address_space(1))) void*)g,
      (__attribute__((address_space(3))) void*)l, 16, 0, 0);
}

// ---------------------------------------------------------------------------
// Router: 256 blocks x 32 tokens, wave-per-token (8 tokens/wave).
// ---------------------------------------------------------------------------
__global__ __launch_bounds__(256) void router3(
    const float* __restrict__ x, const float* __restrict__ Wr,
    float* __restrict__ tprob, int* __restrict__ be_out,
    int* __restrict__ cnt_blk, float* __restrict__ imp_blk)
{
  const int tid = threadIdx.x, lane = tid & 63, wv = tid >> 6;
  const int b = blockIdx.x;
  __shared__ int cnt_l[NEXP];
  __shared__ float imp_l[4][NEXP];
  if (tid < NEXP) cnt_l[tid] = 0;

  float wreg[12][8];
  #pragma unroll
  for (int j = 0; j < 3; ++j)
    #pragma unroll
    for (int q = 0; q < 4; ++q) {
      const float4* p = (const float4*)(Wr + (size_t)(j * 256 + lane * 4 + q) * 8);
      float4 lo = p[0], hi = p[1];
      wreg[j*4+q][0] = lo.x; wreg[j*4+q][1] = lo.y;
      wreg[j*4+q][2] = lo.z; wreg[j*4+q][3] = lo.w;
      wreg[j*4+q][4] = hi.x; wreg[j*4+q][5] = hi.y;
      wreg[j*4+q][6] = hi.z; wreg[j*4+q][7] = hi.w;
    }

  float impacc[NEXP];
  #pragma unroll
  for (int e = 0; e < NEXP; ++e) impacc[e] = 0.0f;
  __syncthreads();

  #pragma unroll 1
  for (int t = 0; t < 8; ++t) {
    const int tok = b * 32 + wv * 8 + t;
    float4 xv[3];
    #pragma unroll
    for (int j = 0; j < 3; ++j)
      xv[j] = *(const float4*)(x + (size_t)tok * CDIM + j * 256 + lane * 4);

    float acc[NEXP];
    #pragma unroll
    for (int e = 0; e < NEXP; ++e) acc[e] = 0.0f;
    #pragma unroll
    for (int j = 0; j < 3; ++j) {
      const float xa[4] = {xv[j].x, xv[j].y, xv[j].z, xv[j].w};
      #pragma unroll
      for (int q = 0; q < 4; ++q)
        #pragma unroll
        for (int e = 0; e < NEXP; ++e)
          acc[e] = fmaf(xa[q], wreg[j*4+q][e], acc[e]);
    }
    #pragma unroll
    for (int e = 0; e < NEXP; ++e) {
      float v = acc[e];
      v += __shfl_xor(v, 1);  v += __shfl_xor(v, 2);  v += __shfl_xor(v, 4);
      v += __shfl_xor(v, 8);  v += __shfl_xor(v, 16); v += __shfl_xor(v, 32);
      acc[e] = v;
    }
    float m = acc[0]; int be = 0;
    #pragma unroll
    for (int e = 1; e < NEXP; ++e) if (acc[e] > m) { m = acc[e]; be = e; }
    float pr[NEXP]; float s = 0.0f;
    #pragma unroll
    for (int e = 0; e < NEXP; ++e) { pr[e] = __expf(acc[e] - m); s += pr[e]; }
    const float inv = 1.0f / s;
    #pragma unroll
    for (int e = 0; e < NEXP; ++e) impacc[e] += pr[e] * inv;
    if (lane == 0) {
      tprob[tok]  = pr[be] * inv;
      be_out[tok] = be;
      atomicAdd(&cnt_l[be], 1);
    }
  }

  if (lane == 0) {
    #pragma unroll
    for (int e = 0; e < NEXP; ++e) imp_l[wv][e] = impacc[e];
  }
  __syncthreads();
  if (tid < NEXP) {
    cnt_blk[b * NEXP + tid] = cnt_l[tid];
    imp_blk[b * NEXP + tid] =
        imp_l[0][tid] + imp_l[1][tid] + imp_l[2][tid] + imp_l[3][tid];
  }
}

// ---------------------------------------------------------------------------
// Scan: per-expert exclusive scan over 256 blocks, 128-aligned offsets,
// counts, importance, aux loss, pad tokmap = -1. No atomics.
// ---------------------------------------------------------------------------
__global__ __launch_bounds__(256) void scan_kernel(
    const int* __restrict__ cnt_blk, const float* __restrict__ imp_blk,
    int* __restrict__ counts, int* __restrict__ off,
    int* __restrict__ base_blk, float* __restrict__ out_aux,
    int* __restrict__ tokmap)
{
  const int tid = threadIdx.x, lane = tid & 63, wv = tid >> 6;
  __shared__ int   wsum[NEXP][4];
  __shared__ float wimp[NEXP][4];
  __shared__ int   off_s[9];
  __shared__ int   cnt_s[NEXP];

  int pref[NEXP];
  #pragma unroll
  for (int e = 0; e < NEXP; ++e) {
    int v = cnt_blk[tid * NEXP + e];
    int inc = v;
    #pragma unroll
    for (int o = 1; o < 64; o <<= 1) {
      int n = __shfl_up(inc, o);
      if (lane >= o) inc += n;
    }
    if (lane == 63) wsum[e][wv] = inc;
    pref[e] = inc - v;

    float f = imp_blk[tid * NEXP + e];
    f += __shfl_xor(f, 1);  f += __shfl_xor(f, 2);  f += __shfl_xor(f, 4);
    f += __shfl_xor(f, 8);  f += __shfl_xor(f, 16); f += __shfl_xor(f, 32);
    if (lane == 0) wimp[e][wv] = f;
  }
  __syncthreads();
  if (tid == 0) {
    int o = 0; float aux = 0.0f;
    #pragma unroll
    for (int e = 0; e < NEXP; ++e) {
      int tot = wsum[e][0] + wsum[e][1] + wsum[e][2] + wsum[e][3];
      float im = wimp[e][0] + wimp[e][1] + wimp[e][2] + wimp[e][3];
      counts[e] = tot;
      cnt_s[e] = tot;
      aux += im * (float)tot;
      off_s[e] = o;
      o += (tot + 127) & ~127;
    }
    off_s[8] = o;
    out_aux[0] = (float)NEXP * aux / ((float)N_TOK * (float)N_TOK);
    for (int i = 0; i < 9; ++i) off[i] = off_s[i];
  }
  __syncthreads();
  #pragma unroll
  for (int e = 0; e < NEXP; ++e) {
    int wofs = 0;
    #pragma unroll
    for (int w = 0; w < 4; ++w) if (w < wv) wofs += wsum[e][w];
    base_blk[tid * NEXP + e] = off_s[e] + wofs + pref[e];
  }
  #pragma unroll 1
  for (int e = 0; e < NEXP; ++e) {
    int p0 = off_s[e] + cnt_s[e], p1 = off_s[e + 1];
    for (int i = p0 + tid; i < p1; i += 256) tokmap[i] = -1;
  }
}

// ---------------------------------------------------------------------------
// Gather: pack routed token rows into xgT [tile128][kc:12][128][64] swizzled.
// ---------------------------------------------------------------------------
__global__ __launch_bounds__(256) void gather2(
    const float* __restrict__ x, const float* __restrict__ tprob,
    const int* __restrict__ be, const int* __restrict__ base_blk,
    bf16* __restrict__ xgT, int* __restrict__ tokmap, float* __restrict__ tpg)
{
  const int tid = threadIdx.x, lane = tid & 63, wv = tid >> 6;
  const int b = blockIdx.x;
  __shared__ int slot_l[32];

  if (wv == 0) {
    const int t = lane;
    const int bet = (t < 32) ? be[b * 32 + t] : -1;
    int slot = -1;
    #pragma unroll
    for (int e = 0; e < NEXP; ++e) {
      unsigned long long msk = __ballot(bet == e);
      if (bet == e) {
        int rank = __popcll(msk & ((1ull << lane) - 1ull));
        slot = base_blk[b * NEXP + e] + rank;
      }
    }
    if (t < 32) {
      slot_l[t] = slot;
      const int tok = b * 32 + t;
      tokmap[slot] = tok;
      tpg[slot] = tprob[tok];
    }
  }
  __syncthreads();

  #pragma unroll 1
  for (int t8 = 0; t8 < 8; ++t8) {
    const int t = wv * 8 + t8;
    const int slot = slot_l[t];
    const int tok = b * 32 + t;
    const int tile = slot >> 7, r = slot & 127;
    #pragma unroll
    for (int j = 0; j < 3; ++j) {
      const int col = j * 256 + lane * 4;
      const int kc = col >> 6, cw = col & 63;
      float4 v = *(const float4*)(x + (size_t)tok * CDIM + col);
      bf16x4 o;
      o[0] = (bf16)v.x; o[1] = (bf16)v.y; o[2] = (bf16)v.z; o[3] = (bf16)v.w;
      char* dst = (char*)xgT + (((size_t)tile * 12 + kc) * 128 + r) * 128
                  + ((cw * 2) ^ ((r & 7) << 4));
      *(bf16x4*)dst = o;
    }
  }
}

// ---------------------------------------------------------------------------
// W [E][R][S] fp32 -> tiled bf16 [E][S/64][R/64][64][64], swizzled rows.
// ---------------------------------------------------------------------------
__global__ __launch_bounds__(256) void transpose_w(
    const float* __restrict__ W, bf16* __restrict__ WT, int R, int S)
{
  __shared__ float t[64][65];
  const int r0 = blockIdx.x * 64, s0 = blockIdx.y * 64, e = blockIdx.z;
  const float* We = W + (size_t)e * R * S;
  const int NT = S >> 6, NK = R >> 6;
  char* outT = (char*)WT + (((size_t)e * NT + (s0 >> 6)) * NK + (r0 >> 6)) * 8192;
  const int tid = threadIdx.x, lr = tid >> 4, lc4 = tid & 15;

  #pragma unroll
  for (int j = 0; j < 4; ++j) {
    int r = lr + j * 16;
    float4 v = *(const float4*)(We + (size_t)(r0 + r) * S + s0 + lc4 * 4);
    t[r][lc4 * 4 + 0] = v.x; t[r][lc4 * 4 + 1] = v.y;
    t[r][lc4 * 4 + 2] = v.z; t[r][lc4 * 4 + 3] = v.w;
  }
  __syncthreads();
  #pragma unroll
  for (int j = 0; j < 4; ++j) {
    int sI = lr + j * 16;
    bf16x4 o;
    #pragma unroll
    for (int q = 0; q < 4; ++q) o[q] = (bf16)t[lc4 * 4 + q][sI];
    *(bf16x4*)(outT + sI * 128 + ((lc4 * 8) ^ ((sI & 7) << 4))) = o;
  }
}

// ---------------------------------------------------------------------------
// Grouped GEMM (round-13 proven pipeline): BM=128, BK=64, 4 waves.
// A: LDS double-buffer (2x16 KB), global_load_lds DMA, depth-2.
// B: single buffer (BN*128 bytes).
// BN=128: waves 2x2 (per-wave 64x64). BN=64: waves 4x1 along M (32x64) ->
// grid doubles for ffn2 (full CU fill) and LDS drops to 40 KB.
// Per iter: barrier; ds_read A(cur)+B; lgkm0+sb; barrier; stage B(k+1) then
// A(k+2); MFMA half0; vmcnt(4); MFMA half1.
// ---------------------------------------------------------------------------
template<int NKC, int NCHN, int BN, bool GELU>
__global__ __launch_bounds__(256, 3) void ffn_p(
    const bf16* __restrict__ Abuf, const bf16* __restrict__ Wt,
    const float* __restrict__ bias, const int* __restrict__ off,
    const int* __restrict__ tokmap, const float* __restrict__ tpg,
    bf16* __restrict__ hbufT, float* __restrict__ y)
{
  constexpr int FM = (BN == 128) ? 4 : 2;        // per-wave m-fragments

  const int bid = blockIdx.x + blockIdx.y * 72;
  const int c  = bid & 7;
  const int r2 = bid >> 3;
  const int bx = c * 9 + (r2 % 9);
  const int by = r2 / 9;

  const int ptot = off[8];
  const int m0 = bx * 128;
  if (m0 >= ptot) return;
  int e = 0;
  #pragma unroll
  for (int q = 0; q < 7; ++q) if (m0 >= off[q + 1]) e = q + 1;

  const int tid = threadIdx.x, lane = tid & 63, wv = tid >> 6;
  const int wr = (BN == 128) ? (wv >> 1) * 64 : wv * 32;
  const int wc = (BN == 128) ? (wv & 1) * 64 : 0;

  __shared__ __attribute__((aligned(1024))) char smem[32768 + BN * 128];
  // A buf0 @0 (16K), A buf1 @16K, B @32K (BN*128)

  const char* aBase = (const char*)Abuf + (size_t)bx * NKC * 16384;
  const char* bBase = (BN == 128)
      ? (const char*)Wt + (((size_t)e * NCHN + by * 2 + (wv >> 1)) * NKC) * 8192
            + (wv & 1) * 4096
      : (const char*)Wt + (((size_t)e * NCHN + by) * NKC) * 8192 + wv * 2048;

  auto stageA = [&](int buf, int kc) {
    const char* aS = aBase + (size_t)kc * 16384 + wv * 4096 + lane * 16;
    char* ab = smem + buf * 16384;
    #pragma unroll
    for (int i = 0; i < 4; ++i)
      load16_lds(aS + i * 1024, ab + wv * 4096 + i * 1024);
  };
  auto stageB = [&](int kc) {
    const char* bS = bBase + (size_t)kc * 8192 + lane * 16;
    char* bb = smem + 32768 + ((BN == 128) ? wv * 4096 : wv * 2048);
    #pragma unroll
    for (int i = 0; i < BN / 32; ++i)
      load16_lds(bS + i * 1024, bb + i * 1024);
  };

  // hoisted swizzled byte offsets (lane-constant across the K-loop)
  int aoff[2][FM], boff[2][4];
  #pragma unroll
  for (int kk = 0; kk < 2; ++kk) {
    #pragma unroll
    for (int f = 0; f < FM; ++f) {
      int rowA = wr + f * 16 + (lane & 15);
      int ba   = rowA * 128 + kk * 64 + (lane >> 4) * 16;
      aoff[kk][f] = ba ^ ((rowA & 7) << 4);
    }
    #pragma unroll
    for (int f = 0; f < 4; ++f) {
      int rowB = wc + f * 16 + (lane & 15);
      int bb   = rowB * 128 + kk * 64 + (lane >> 4) * 16;
      boff[kk][f] = bb ^ ((rowB & 7) << 4);
    }
  }

  f32x4 acc[FM][4];
  #pragma unroll
  for (int i = 0; i < FM; ++i)
    #pragma unroll
    for (int j = 0; j < 4; ++j)
      #pragma unroll
      for (int q = 0; q < 4; ++q) acc[i][j][q] = 0.0f;

  // prologue: A0, B0, A1 issued; vmcnt(4) leaves A1's 4 loads in flight
  stageA(0, 0);
  stageB(0);
  stageA(1, 1);
  asm volatile("s_waitcnt vmcnt(4)" ::: "memory");

  for (int kc = 0; kc < NKC; ++kc) {
    const int cur = kc & 1;
    __builtin_amdgcn_s_barrier();          // A(cur) and B(kc) resident
    const char* A = smem + cur * 16384;
    const char* B = smem + 32768;
    bf16x8 af[2][FM], bfr[2][4];
    #pragma unroll
    for (int kk = 0; kk < 2; ++kk) {
      #pragma unroll
      for (int f = 0; f < FM; ++f) af[kk][f] = *(const bf16x8*)(A + aoff[kk][f]);
      #pragma unroll
      for (int f = 0; f < 4; ++f) bfr[kk][f] = *(const bf16x8*)(B + boff[kk][f]);
    }
    asm volatile("s_waitcnt lgkmcnt(0)" ::: "memory");
    __builtin_amdgcn_sched_barrier(0);     // rule #18: pin reads before barrier
    __builtin_amdgcn_s_barrier();          // all waves done reading A(cur), B
    if (kc + 1 < NKC) stageB(kc + 1);      // B first (drained by vmcnt(4))
    if (kc + 2 < NKC) stageA(cur, kc + 2); // A last (newest 4, stays in flight)

    __builtin_amdgcn_s_setprio(1);
    #pragma unroll
    for (int fm = 0; fm < FM; ++fm)
      #pragma unroll
      for (int fn = 0; fn < 4; ++fn)
        acc[fm][fn] = __builtin_amdgcn_mfma_f32_16x16x32_bf16(
            af[0][fm], bfr[0][fn], acc[fm][fn], 0, 0, 0);
    __builtin_amdgcn_s_setprio(0);

    if (kc + 1 < NKC) {
      __builtin_amdgcn_sched_barrier(0);
      if (kc + 2 < NKC)
        asm volatile("s_waitcnt vmcnt(4)" ::: "memory");  // A(k+2) flies
      else
        asm volatile("s_waitcnt vmcnt(0)" ::: "memory");  // tail drain
      __builtin_amdgcn_sched_barrier(0);
    }

    __builtin_amdgcn_s_setprio(1);
    #pragma unroll
    for (int fm = 0; fm < FM; ++fm)
      #pragma unroll
      for (int fn = 0; fn < 4; ++fn)
        acc[fm][fn] = __builtin_amdgcn_mfma_f32_16x16x32_bf16(
            af[1][fm], bfr[1][fn], acc[fm][fn], 0, 0, 0);
    __builtin_amdgcn_s_setprio(0);
  }
  __syncthreads();     // epilogue reuses smem

  const int g = lane >> 4, ci = lane & 15;
  float bv[4];
  #pragma unroll
  for (int fn = 0; fn < 4; ++fn)
    bv[fn] = bias[e * (NCHN * 64) + by * BN + wc + fn * 16 + ci];

  if constexpr (GELU) {
    // bias + tanh-GELU -> swizzled bf16 C tile (32 KB) -> linear copy to hbufT
    #pragma unroll
    for (int fm = 0; fm < FM; ++fm)
      #pragma unroll
      for (int fn = 0; fn < 4; ++fn)
        #pragma unroll
        for (int rg = 0; rg < 4; ++rg) {
          int row = wr + fm * 16 + g * 4 + rg;
          int col = wc + fn * 16 + ci;
          float v = acc[fm][fn][rg] + bv[fn];
          float t3 = v + 0.044715f * v * v * v;
          float gel = v / (1.0f + __expf(-1.5957691216f * t3));
          int chunk = col >> 6, cw = col & 63;
          int byte = chunk * 16384 + row * 128 + ((cw * 2) ^ ((row & 7) << 4));
          *(bf16*)(smem + byte) = (bf16)gel;
        }
    __syncthreads();
    char* hdst = (char*)hbufT + ((size_t)bx * 48 + by * 2) * 16384;
    #pragma unroll
    for (int i = 0; i < 8; ++i) {
      int bo = (i * 256 + tid) * 16;
      *(f32x4*)(hdst + bo) = *(const f32x4*)(smem + bo);
    }
  } else {
    // bias + tprob -> f32 tile [128][BN=64] (32 KB), single phase -> scatter
    float tp[FM][4];
    #pragma unroll
    for (int fm = 0; fm < FM; ++fm)
      #pragma unroll
      for (int rg = 0; rg < 4; ++rg)
        tp[fm][rg] = tpg[m0 + wr + fm * 16 + g * 4 + rg];
    float* smemf = (float*)smem;
    #pragma unroll
    for (int fm = 0; fm < FM; ++fm)
      #pragma unroll
      for (int fn = 0; fn < 4; ++fn)
        #pragma unroll
        for (int rg = 0; rg < 4; ++rg) {
          int row = wr + fm * 16 + g * 4 + rg;
          int col = fn * 16 + ci;
          smemf[row * 64 + col] = (acc[fm][fn][rg] + bv[fn]) * tp[fm][rg];
        }
    __syncthreads();
    // 128 rows x 16 f32x4 = 2048 vec4s, 8 per thread
    #pragma unroll
    for (int it = 0; it < 8; ++it) {
      int lin = it * 256 + tid;
      int row = lin >> 4;
      int c4  = lin & 15;
      int tokr = tokmap[m0 + row];
      f32x4 v = *(const f32x4*)(smemf + row * 64 + c4 * 4);
      if (tokr >= 0)
        *(f32x4*)(y + (size_t)tokr * CDIM + by * 64 + c4 * 4) = v;
    }
  }
}

// ---------------------------------------------------------------------------
extern "C" void kernel_launch(void* const* d_in, const int* in_sizes, int n_in,
                              void* d_out, int out_size, void* d_ws, size_t ws_size,
                              hipStream_t stream)
{
  const float* x  = (const float*)d_in[0];
  const float* Wr = (const float*)d_in[1];
  const float* W1 = (const float*)d_in[2];
  const float* b1 = (const float*)d_in[3];
  const float* W2 = (const float*)d_in[4];
  const float* b2 = (const float*)d_in[5];
  float* out = (float*)d_out;

  char* ws = (char*)d_ws;
  int*   be         = (int*)(ws + WS_BE);
  float* tprob      = (float*)(ws + WS_TPROB);
  int*   cnt_blk    = (int*)(ws + WS_CNTB);
  float* imp_blk    = (float*)(ws + WS_IMPB);
  int*   base_blk   = (int*)(ws + WS_BASEB);
  int*   counts     = (int*)(ws + WS_CNT);
  int*   off        = (int*)(ws + WS_OFF);
  int*   tokmap     = (int*)(ws + WS_TOKMAP);
  float* tpg        = (float*)(ws + WS_TPG);
  bf16*  xgT        = (bf16*)(ws + WS_XGT);
  bf16*  w1tT       = (bf16*)(ws + WS_W1T);
  bf16*  hbufT      = (bf16*)(ws + WS_HBUF);
  bf16*  w2tT       = (bf16*)(ws + WS_W2T);   // written after ffn1

  router3<<<dim3(NBLK), 256, 0, stream>>>(x, Wr, tprob, be, cnt_blk, imp_blk);
  scan_kernel<<<dim3(1), 256, 0, stream>>>(cnt_blk, imp_blk, counts, off,
                                           base_blk, out + (size_t)N_TOK * CDIM,
                                           tokmap);
  gather2<<<dim3(NBLK), 256, 0, stream>>>(x, tprob, be, base_blk,
                                          xgT, tokmap, tpg);
  transpose_w<<<dim3(CDIM / 64, HDIM / 64, NEXP), 256, 0, stream>>>(
      W1, w1tT, CDIM, HDIM);
  ffn_p<12, 48, 128, true><<<dim3(72, 24), 256, 0, stream>>>(
      xgT, w1tT, b1, off, nullptr, nullptr, hbufT, nullptr);
  transpose_w<<<dim3(HDIM / 64, CDIM / 64, NEXP), 256, 0, stream>>>(
      W2, w2tT, HDIM, CDIM);
  ffn_p<48, 12, 64, false><<<dim3(72, 12), 256, 0, stream>>>(
      hbufT, w2tT, b2, off, tokmap, tpg, nullptr, out);
}

// Round 16
// 169.547 us; speedup vs baseline: 1.2282x; 1.0830x over previous
//
#include <hip/hip_runtime.h>
#include <hip/hip_bf16.h>
#include <cstdint>
#include <cmath>

#define N_TOK 8192
#define CDIM  768
#define HDIM  3072
#define NEXP  8
#define NBLK  256     // router/gather blocks, 32 tokens each

typedef __bf16 bf16;
typedef __bf16 bf16x4 __attribute__((ext_vector_type(4)));
typedef __bf16 bf16x8 __attribute__((ext_vector_type(8)));
typedef float  f32x4  __attribute__((ext_vector_type(4)));

// ws byte offsets
#define WS_BE      0u          // 8192 int
#define WS_TPROB   32768u      // 8192 f32
#define WS_CNTB    65536u      // 256*8 int
#define WS_IMPB    73728u      // 256*8 f32
#define WS_BASEB   81920u      // 256*8 int
#define WS_CNT     90112u      // 8 int
#define WS_OFF     90176u      // 9 int
#define WS_TOKMAP  98304u      // 9216 int
#define WS_TPG     137216u     // 9216 f32  -> ends 174080
#define WS_XGT     (1u<<20)    // 72*12*16384 = 14,155,776
#define WS_W1T     (16u<<20)   // 37,748,736 -> ends 54,525,952
#define WS_HBUF    (56u<<20)   // 72*48*16384 = 56,623,104 -> ends 115,343,360
#define WS_W2T     (1u<<20)    // aliases XGT/W1T, written after ffn1

__device__ __forceinline__ void load16_lds(const void* g, void* l) {
  __builtin_amdgcn_global_load_lds(
      (const __attribute__((address_space(1))) void*)g,
      (__attribute__((address_space(3))) void*)l, 16, 0, 0);
}

// ---------------------------------------------------------------------------
// Shared transpose body: W [E][R][S] fp32 -> tiled bf16
// [E][S/64][R/64][64][64], swizzled rows. Callable from merged kernels.
// ---------------------------------------------------------------------------
__device__ __forceinline__ void transpose_body(
    const float* __restrict__ W, bf16* __restrict__ WT, int R, int S,
    int xI, int yI, int e, int tid, float (*t)[65])
{
  const int r0 = xI * 64, s0 = yI * 64;
  const float* We = W + (size_t)e * R * S;
  const int NT = S >> 6, NK = R >> 6;
  char* outT = (char*)WT + (((size_t)e * NT + yI) * NK + xI) * 8192;
  const int lr = tid >> 4, lc4 = tid & 15;

  #pragma unroll
  for (int j = 0; j < 4; ++j) {
    int r = lr + j * 16;
    float4 v = *(const float4*)(We + (size_t)(r0 + r) * S + s0 + lc4 * 4);
    t[r][lc4 * 4 + 0] = v.x; t[r][lc4 * 4 + 1] = v.y;
    t[r][lc4 * 4 + 2] = v.z; t[r][lc4 * 4 + 3] = v.w;
  }
  __syncthreads();
  #pragma unroll
  for (int j = 0; j < 4; ++j) {
    int sI = lr + j * 16;
    bf16x4 o;
    #pragma unroll
    for (int q = 0; q < 4; ++q) o[q] = (bf16)t[lc4 * 4 + q][sI];
    *(bf16x4*)(outT + sI * 128 + ((lc4 * 8) ^ ((sI & 7) << 4))) = o;
  }
}

// ---------------------------------------------------------------------------
// Merged: blocks [0,256) run the router (32 tokens each, wave-per-token);
// blocks [256, 256+4608) transpose W1 -> w1tT. Disjoint data, independent.
// ---------------------------------------------------------------------------
__global__ __launch_bounds__(256) void router_t1(
    const float* __restrict__ x, const float* __restrict__ Wr,
    float* __restrict__ tprob, int* __restrict__ be_out,
    int* __restrict__ cnt_blk, float* __restrict__ imp_blk,
    const float* __restrict__ W1, bf16* __restrict__ w1tT)
{
  __shared__ float smem_t[64][65];
  const int tid = threadIdx.x, lane = tid & 63, wv = tid >> 6;

  if (blockIdx.x >= NBLK) {
    // ---- W1 transpose branch: grid (12, 48, 8) flattened
    const int tb = blockIdx.x - NBLK;
    const int xI = tb % 12, yI = (tb / 12) % 48, e = tb / 576;
    transpose_body(W1, w1tT, CDIM, HDIM, xI, yI, e, tid, smem_t);
    return;
  }

  // ---- router branch
  int* cnt_l = (int*)&smem_t[0][0];          // 8 ints
  float (*imp_l)[NEXP] = (float(*)[NEXP])&smem_t[1][0];
  const int b = blockIdx.x;
  if (tid < NEXP) cnt_l[tid] = 0;

  float wreg[12][8];
  #pragma unroll
  for (int j = 0; j < 3; ++j)
    #pragma unroll
    for (int q = 0; q < 4; ++q) {
      const float4* p = (const float4*)(Wr + (size_t)(j * 256 + lane * 4 + q) * 8);
      float4 lo = p[0], hi = p[1];
      wreg[j*4+q][0] = lo.x; wreg[j*4+q][1] = lo.y;
      wreg[j*4+q][2] = lo.z; wreg[j*4+q][3] = lo.w;
      wreg[j*4+q][4] = hi.x; wreg[j*4+q][5] = hi.y;
      wreg[j*4+q][6] = hi.z; wreg[j*4+q][7] = hi.w;
    }

  float impacc[NEXP];
  #pragma unroll
  for (int e = 0; e < NEXP; ++e) impacc[e] = 0.0f;
  __syncthreads();

  #pragma unroll 1
  for (int t = 0; t < 8; ++t) {
    const int tok = b * 32 + wv * 8 + t;
    float4 xv[3];
    #pragma unroll
    for (int j = 0; j < 3; ++j)
      xv[j] = *(const float4*)(x + (size_t)tok * CDIM + j * 256 + lane * 4);

    float acc[NEXP];
    #pragma unroll
    for (int e = 0; e < NEXP; ++e) acc[e] = 0.0f;
    #pragma unroll
    for (int j = 0; j < 3; ++j) {
      const float xa[4] = {xv[j].x, xv[j].y, xv[j].z, xv[j].w};
      #pragma unroll
      for (int q = 0; q < 4; ++q)
        #pragma unroll
        for (int e = 0; e < NEXP; ++e)
          acc[e] = fmaf(xa[q], wreg[j*4+q][e], acc[e]);
    }
    #pragma unroll
    for (int e = 0; e < NEXP; ++e) {
      float v = acc[e];
      v += __shfl_xor(v, 1);  v += __shfl_xor(v, 2);  v += __shfl_xor(v, 4);
      v += __shfl_xor(v, 8);  v += __shfl_xor(v, 16); v += __shfl_xor(v, 32);
      acc[e] = v;
    }
    float m = acc[0]; int be = 0;
    #pragma unroll
    for (int e = 1; e < NEXP; ++e) if (acc[e] > m) { m = acc[e]; be = e; }
    float pr[NEXP]; float s = 0.0f;
    #pragma unroll
    for (int e = 0; e < NEXP; ++e) { pr[e] = __expf(acc[e] - m); s += pr[e]; }
    const float inv = 1.0f / s;
    #pragma unroll
    for (int e = 0; e < NEXP; ++e) impacc[e] += pr[e] * inv;
    if (lane == 0) {
      tprob[tok]  = pr[be] * inv;
      be_out[tok] = be;
      atomicAdd(&cnt_l[be], 1);
    }
  }

  if (lane == 0) {
    #pragma unroll
    for (int e = 0; e < NEXP; ++e) imp_l[wv][e] = impacc[e];
  }
  __syncthreads();
  if (tid < NEXP) {
    cnt_blk[b * NEXP + tid] = cnt_l[tid];
    imp_blk[b * NEXP + tid] =
        imp_l[0][tid] + imp_l[1][tid] + imp_l[2][tid] + imp_l[3][tid];
  }
}

// ---------------------------------------------------------------------------
// Standalone transpose (used for W2 after ffn1).
// ---------------------------------------------------------------------------
__global__ __launch_bounds__(256) void transpose_w(
    const float* __restrict__ W, bf16* __restrict__ WT, int R, int S)
{
  __shared__ float t[64][65];
  transpose_body(W, WT, R, S, blockIdx.x, blockIdx.y, blockIdx.z,
                 threadIdx.x, t);
}

// ---------------------------------------------------------------------------
// Scan: per-expert exclusive scan over 256 blocks, 128-aligned offsets,
// counts, importance, aux loss, pad tokmap = -1. No atomics.
// ---------------------------------------------------------------------------
__global__ __launch_bounds__(256) void scan_kernel(
    const int* __restrict__ cnt_blk, const float* __restrict__ imp_blk,
    int* __restrict__ counts, int* __restrict__ off,
    int* __restrict__ base_blk, float* __restrict__ out_aux,
    int* __restrict__ tokmap)
{
  const int tid = threadIdx.x, lane = tid & 63, wv = tid >> 6;
  __shared__ int   wsum[NEXP][4];
  __shared__ float wimp[NEXP][4];
  __shared__ int   off_s[9];
  __shared__ int   cnt_s[NEXP];

  int pref[NEXP];
  #pragma unroll
  for (int e = 0; e < NEXP; ++e) {
    int v = cnt_blk[tid * NEXP + e];
    int inc = v;
    #pragma unroll
    for (int o = 1; o < 64; o <<= 1) {
      int n = __shfl_up(inc, o);
      if (lane >= o) inc += n;
    }
    if (lane == 63) wsum[e][wv] = inc;
    pref[e] = inc - v;

    float f = imp_blk[tid * NEXP + e];
    f += __shfl_xor(f, 1);  f += __shfl_xor(f, 2);  f += __shfl_xor(f, 4);
    f += __shfl_xor(f, 8);  f += __shfl_xor(f, 16); f += __shfl_xor(f, 32);
    if (lane == 0) wimp[e][wv] = f;
  }
  __syncthreads();
  if (tid == 0) {
    int o = 0; float aux = 0.0f;
    #pragma unroll
    for (int e = 0; e < NEXP; ++e) {
      int tot = wsum[e][0] + wsum[e][1] + wsum[e][2] + wsum[e][3];
      float im = wimp[e][0] + wimp[e][1] + wimp[e][2] + wimp[e][3];
      counts[e] = tot;
      cnt_s[e] = tot;
      aux += im * (float)tot;
      off_s[e] = o;
      o += (tot + 127) & ~127;
    }
    off_s[8] = o;
    out_aux[0] = (float)NEXP * aux / ((float)N_TOK * (float)N_TOK);
    for (int i = 0; i < 9; ++i) off[i] = off_s[i];
  }
  __syncthreads();
  #pragma unroll
  for (int e = 0; e < NEXP; ++e) {
    int wofs = 0;
    #pragma unroll
    for (int w = 0; w < 4; ++w) if (w < wv) wofs += wsum[e][w];
    base_blk[tid * NEXP + e] = off_s[e] + wofs + pref[e];
  }
  #pragma unroll 1
  for (int e = 0; e < NEXP; ++e) {
    int p0 = off_s[e] + cnt_s[e], p1 = off_s[e + 1];
    for (int i = p0 + tid; i < p1; i += 256) tokmap[i] = -1;
  }
}

// ---------------------------------------------------------------------------
// Gather: pack routed token rows into xgT [tile128][kc:12][128][64] swizzled.
// ---------------------------------------------------------------------------
__global__ __launch_bounds__(256) void gather2(
    const float* __restrict__ x, const float* __restrict__ tprob,
    const int* __restrict__ be, const int* __restrict__ base_blk,
    bf16* __restrict__ xgT, int* __restrict__ tokmap, float* __restrict__ tpg)
{
  const int tid = threadIdx.x, lane = tid & 63, wv = tid >> 6;
  const int b = blockIdx.x;
  __shared__ int slot_l[32];

  if (wv == 0) {
    const int t = lane;
    const int bet = (t < 32) ? be[b * 32 + t] : -1;
    int slot = -1;
    #pragma unroll
    for (int e = 0; e < NEXP; ++e) {
      unsigned long long msk = __ballot(bet == e);
      if (bet == e) {
        int rank = __popcll(msk & ((1ull << lane) - 1ull));
        slot = base_blk[b * NEXP + e] + rank;
      }
    }
    if (t < 32) {
      slot_l[t] = slot;
      const int tok = b * 32 + t;
      tokmap[slot] = tok;
      tpg[slot] = tprob[tok];
    }
  }
  __syncthreads();

  #pragma unroll 1
  for (int t8 = 0; t8 < 8; ++t8) {
    const int t = wv * 8 + t8;
    const int slot = slot_l[t];
    const int tok = b * 32 + t;
    const int tile = slot >> 7, r = slot & 127;
    #pragma unroll
    for (int j = 0; j < 3; ++j) {
      const int col = j * 256 + lane * 4;
      const int kc = col >> 6, cw = col & 63;
      float4 v = *(const float4*)(x + (size_t)tok * CDIM + col);
      bf16x4 o;
      o[0] = (bf16)v.x; o[1] = (bf16)v.y; o[2] = (bf16)v.z; o[3] = (bf16)v.w;
      char* dst = (char*)xgT + (((size_t)tile * 12 + kc) * 128 + r) * 128
                  + ((cw * 2) ^ ((r & 7) << 4));
      *(bf16x4*)dst = o;
    }
  }
}

// ---------------------------------------------------------------------------
// Grouped GEMM (round-13 proven, best measured): BM=128, BN=128, BK=64,
// 4 waves. A: LDS double-buffer (2x16 KB), global_load_lds DMA, depth-2.
// B: single buffer (16 KB) -> 48 KB LDS -> 3 blocks/CU at (256,3).
// Per iter: barrier; ds_read A(cur)+B; lgkm0+sb; barrier; stage B(k+1) then
// A(k+2); MFMA half0; vmcnt(4); MFMA half1.
// ---------------------------------------------------------------------------
template<int NKC, int NCHN, bool GELU>
__global__ __launch_bounds__(256, 3) void ffn_p(
    const bf16* __restrict__ Abuf, const bf16* __restrict__ Wt,
    const float* __restrict__ bias, const int* __restrict__ off,
    const int* __restrict__ tokmap, const float* __restrict__ tpg,
    bf16* __restrict__ hbufT, float* __restrict__ y)
{
  const int bid = blockIdx.x + blockIdx.y * 72;
  const int c  = bid & 7;
  const int r2 = bid >> 3;
  const int bx = c * 9 + (r2 % 9);
  const int by = r2 / 9;

  const int ptot = off[8];
  const int m0 = bx * 128;
  if (m0 >= ptot) return;
  int e = 0;
  #pragma unroll
  for (int q = 0; q < 7; ++q) if (m0 >= off[q + 1]) e = q + 1;

  const int tid = threadIdx.x, lane = tid & 63, wv = tid >> 6;
  const int wr = (wv >> 1) * 64;
  const int wc = (wv & 1) * 64;

  __shared__ __attribute__((aligned(1024))) char smem[49152];
  // A buf0 @0 (16K), A buf1 @16K, B @32K (16K)

  const char* aBase = (const char*)Abuf + (size_t)bx * NKC * 16384;
  const char* bBase = (const char*)Wt +
      (((size_t)e * NCHN + by * 2 + (wv >> 1)) * NKC) * 8192 + (wv & 1) * 4096;

  auto stageA = [&](int buf, int kc) {
    const char* aS = aBase + (size_t)kc * 16384 + wv * 4096 + lane * 16;
    char* ab = smem + buf * 16384;
    #pragma unroll
    for (int i = 0; i < 4; ++i)
      load16_lds(aS + i * 1024, ab + wv * 4096 + i * 1024);
  };
  auto stageB = [&](int kc) {
    const char* bS = bBase + (size_t)kc * 8192 + lane * 16;
    char* bb = smem + 32768;
    #pragma unroll
    for (int i = 0; i < 4; ++i)
      load16_lds(bS + i * 1024, bb + wv * 4096 + i * 1024);
  };

  // hoisted swizzled byte offsets (lane-constant across the K-loop)
  int aoff[2][4], boff[2][4];
  #pragma unroll
  for (int kk = 0; kk < 2; ++kk)
    #pragma unroll
    for (int f = 0; f < 4; ++f) {
      int rowA = wr + f * 16 + (lane & 15);
      int ba   = rowA * 128 + kk * 64 + (lane >> 4) * 16;
      aoff[kk][f] = ba ^ ((rowA & 7) << 4);
      int rowB = wc + f * 16 + (lane & 15);
      int bb   = rowB * 128 + kk * 64 + (lane >> 4) * 16;
      boff[kk][f] = bb ^ ((rowB & 7) << 4);
    }

  f32x4 acc[4][4];
  #pragma unroll
  for (int i = 0; i < 4; ++i)
    #pragma unroll
    for (int j = 0; j < 4; ++j)
      #pragma unroll
      for (int q = 0; q < 4; ++q) acc[i][j][q] = 0.0f;

  // prologue: A0, B0, A1 issued; vmcnt(4) leaves A1's 4 loads in flight
  stageA(0, 0);
  stageB(0);
  stageA(1, 1);
  asm volatile("s_waitcnt vmcnt(4)" ::: "memory");

  for (int kc = 0; kc < NKC; ++kc) {
    const int cur = kc & 1;
    __builtin_amdgcn_s_barrier();          // A(cur) and B(kc) resident
    const char* A = smem + cur * 16384;
    const char* B = smem + 32768;
    bf16x8 af[2][4], bfr[2][4];
    #pragma unroll
    for (int kk = 0; kk < 2; ++kk) {
      #pragma unroll
      for (int f = 0; f < 4; ++f) af[kk][f]  = *(const bf16x8*)(A + aoff[kk][f]);
      #pragma unroll
      for (int f = 0; f < 4; ++f) bfr[kk][f] = *(const bf16x8*)(B + boff[kk][f]);
    }
    asm volatile("s_waitcnt lgkmcnt(0)" ::: "memory");
    __builtin_amdgcn_sched_barrier(0);     // rule #18: pin reads before barrier
    __builtin_amdgcn_s_barrier();          // all waves done reading A(cur), B
    if (kc + 1 < NKC) stageB(kc + 1);      // B first (drained by vmcnt(4))
    if (kc + 2 < NKC) stageA(cur, kc + 2); // A last (newest 4, stays in flight)

    __builtin_amdgcn_s_setprio(1);
    #pragma unroll
    for (int fm = 0; fm < 4; ++fm)
      #pragma unroll
      for (int fn = 0; fn < 4; ++fn)
        acc[fm][fn] = __builtin_amdgcn_mfma_f32_16x16x32_bf16(
            af[0][fm], bfr[0][fn], acc[fm][fn], 0, 0, 0);
    __builtin_amdgcn_s_setprio(0);

    if (kc + 1 < NKC) {
      __builtin_amdgcn_sched_barrier(0);
      if (kc + 2 < NKC)
        asm volatile("s_waitcnt vmcnt(4)" ::: "memory");  // A(k+2) flies
      else
        asm volatile("s_waitcnt vmcnt(0)" ::: "memory");  // tail drain
      __builtin_amdgcn_sched_barrier(0);
    }

    __builtin_amdgcn_s_setprio(1);
    #pragma unroll
    for (int fm = 0; fm < 4; ++fm)
      #pragma unroll
      for (int fn = 0; fn < 4; ++fn)
        acc[fm][fn] = __builtin_amdgcn_mfma_f32_16x16x32_bf16(
            af[1][fm], bfr[1][fn], acc[fm][fn], 0, 0, 0);
    __builtin_amdgcn_s_setprio(0);
  }
  __syncthreads();     // epilogue reuses smem

  const int g = lane >> 4, ci = lane & 15;
  float bv[4];
  #pragma unroll
  for (int fn = 0; fn < 4; ++fn)
    bv[fn] = bias[e * (NCHN * 64) + by * 128 + wc + fn * 16 + ci];

  if constexpr (GELU) {
    // bias + tanh-GELU -> swizzled bf16 C tile (32 KB) -> linear copy to hbufT
    #pragma unroll
    for (int fm = 0; fm < 4; ++fm)
      #pragma unroll
      for (int fn = 0; fn < 4; ++fn)
        #pragma unroll
        for (int rg = 0; rg < 4; ++rg) {
          int row = wr + fm * 16 + g * 4 + rg;
          int col = wc + fn * 16 + ci;
          float v = acc[fm][fn][rg] + bv[fn];
          float t3 = v + 0.044715f * v * v * v;
          float gel = v / (1.0f + __expf(-1.5957691216f * t3));
          int chunk = col >> 6, cw = col & 63;
          int byte = chunk * 16384 + row * 128 + ((cw * 2) ^ ((row & 7) << 4));
          *(bf16*)(smem + byte) = (bf16)gel;
        }
    __syncthreads();
    char* hdst = (char*)hbufT + ((size_t)bx * 48 + by * 2) * 16384;
    #pragma unroll
    for (int i = 0; i < 8; ++i) {
      int bo = (i * 256 + tid) * 16;
      *(f32x4*)(hdst + bo) = *(const f32x4*)(smem + bo);
    }
  } else {
    // bias + tprob -> two [128][68]-f32 col-halves (34 KB each) -> scatter
    float tp[4][4];
    #pragma unroll
    for (int fm = 0; fm < 4; ++fm)
      #pragma unroll
      for (int rg = 0; rg < 4; ++rg)
        tp[fm][rg] = tpg[m0 + wr + fm * 16 + g * 4 + rg];
    float* smemf = (float*)smem;
    #pragma unroll
    for (int h = 0; h < 2; ++h) {
      if ((wv & 1) == h) {
        #pragma unroll
        for (int fm = 0; fm < 4; ++fm)
          #pragma unroll
          for (int fn = 0; fn < 4; ++fn)
            #pragma unroll
            for (int rg = 0; rg < 4; ++rg) {
              int row = wr + fm * 16 + g * 4 + rg;
              int cl  = fn * 16 + ci;                // 0..63 within half
              smemf[row * 68 + cl] = (acc[fm][fn][rg] + bv[fn]) * tp[fm][rg];
            }
      }
      __syncthreads();
      // full half: 128 rows x 16 f32x4 = 2048 vec4s, 8 per thread
      #pragma unroll
      for (int it = 0; it < 8; ++it) {
        int lin = it * 256 + tid;
        int row = lin >> 4;
        int c4  = lin & 15;
        int tokr = tokmap[m0 + row];
        f32x4 v = *(const f32x4*)(smemf + row * 68 + c4 * 4);
        if (tokr >= 0)
          *(f32x4*)(y + (size_t)tokr * CDIM + by * 128 + h * 64 + c4 * 4) = v;
      }
      __syncthreads();
    }
  }
}

// ---------------------------------------------------------------------------
extern "C" void kernel_launch(void* const* d_in, const int* in_sizes, int n_in,
                              void* d_out, int out_size, void* d_ws, size_t ws_size,
                              hipStream_t stream)
{
  const float* x  = (const float*)d_in[0];
  const float* Wr = (const float*)d_in[1];
  const float* W1 = (const float*)d_in[2];
  const float* b1 = (const float*)d_in[3];
  const float* W2 = (const float*)d_in[4];
  const float* b2 = (const float*)d_in[5];
  float* out = (float*)d_out;

  char* ws = (char*)d_ws;
  int*   be         = (int*)(ws + WS_BE);
  float* tprob      = (float*)(ws + WS_TPROB);
  int*   cnt_blk    = (int*)(ws + WS_CNTB);
  float* imp_blk    = (float*)(ws + WS_IMPB);
  int*   base_blk   = (int*)(ws + WS_BASEB);
  int*   counts     = (int*)(ws + WS_CNT);
  int*   off        = (int*)(ws + WS_OFF);
  int*   tokmap     = (int*)(ws + WS_TOKMAP);
  float* tpg        = (float*)(ws + WS_TPG);
  bf16*  xgT        = (bf16*)(ws + WS_XGT);
  bf16*  w1tT       = (bf16*)(ws + WS_W1T);
  bf16*  hbufT      = (bf16*)(ws + WS_HBUF);
  bf16*  w2tT       = (bf16*)(ws + WS_W2T);   // written after ffn1

  // router (256 blocks) + W1 transpose (4608 blocks) merged
  router_t1<<<dim3(NBLK + 4608), 256, 0, stream>>>(
      x, Wr, tprob, be, cnt_blk, imp_blk, W1, w1tT);
  scan_kernel<<<dim3(1), 256, 0, stream>>>(cnt_blk, imp_blk, counts, off,
                                           base_blk, out + (size_t)N_TOK * CDIM,
                                           tokmap);
  gather2<<<dim3(NBLK), 256, 0, stream>>>(x, tprob, be, base_blk,
                                          xgT, tokmap, tpg);
  ffn_p<12, 48, true><<<dim3(72, 24), 256, 0, stream>>>(
      xgT, w1tT, b1, off, nullptr, nullptr, hbufT, nullptr);
  transpose_w<<<dim3(HDIM / 64, CDIM / 64, NEXP), 256, 0, stream>>>(
      W2, w2tT, HDIM, CDIM);
  ffn_p<48, 12, false><<<dim3(72, 6), 256, 0, stream>>>(
      hbufT, w2tT, b2, off, tokmap, tpg, nullptr, out);
}

// Round 17
// 167.271 us; speedup vs baseline: 1.2449x; 1.0136x over previous
//
#include <hip/hip_runtime.h>
#include <hip/hip_bf16.h>
#include <cstdint>
#include <cmath>

#define N_TOK 8192
#define CDIM  768
#define HDIM  3072
#define NEXP  8
#define NBLK  256     // router/gather blocks, 32 tokens each

typedef __bf16 bf16;
typedef __bf16 bf16x4 __attribute__((ext_vector_type(4)));
typedef __bf16 bf16x8 __attribute__((ext_vector_type(8)));
typedef float  f32x4  __attribute__((ext_vector_type(4)));

// ws byte offsets  (ws_size >= 138,739,712 proven: round-2 big path ran)
#define WS_BE      0u          // 8192 int
#define WS_TPROB   32768u      // 8192 f32
#define WS_CNTB    65536u      // 256*8 int
#define WS_IMPB    73728u      // 256*8 f32
#define WS_BASEB   81920u      // 256*8 int
#define WS_CNT     90112u      // 8 int
#define WS_OFF     90176u      // 9 int
#define WS_TOKMAP  98304u      // 9216 int
#define WS_TPG     137216u     // 9216 f32  -> ends 174080
#define WS_XGT     (1u<<20)    // 72*12*16384 = 14,155,776
#define WS_W1T     (16u<<20)   // 37,748,736 -> ends 54,525,952
#define WS_HBUF    (56u<<20)   // 72*48*16384 = 56,623,104 -> ends 115,343,360
#define WS_W2LO    (16u<<20)   // experts 0-3, aliases w1tT (dead after ffn1)
#define WS_W2HI    115343360u  // experts 4-7, tail: 18,874,368 -> 134,217,728

#define EXP_WSTRIDE 4718592u   // per-expert tiled-weight bytes (both FFNs)

__device__ __forceinline__ void load16_lds(const void* g, void* l) {
  __builtin_amdgcn_global_load_lds(
      (const __attribute__((address_space(1))) void*)g,
      (__attribute__((address_space(3))) void*)l, 16, 0, 0);
}

// ---------------------------------------------------------------------------
// Shared transpose body: W [E][R][S] fp32 -> tiled bf16
// [E][S/64][R/64][64][64], swizzled rows. Callable from merged kernels.
// ---------------------------------------------------------------------------
__device__ __forceinline__ void transpose_body(
    const float* __restrict__ W, bf16* __restrict__ WT, int R, int S,
    int xI, int yI, int e, int tid, float (*t)[65])
{
  const int r0 = xI * 64, s0 = yI * 64;
  const float* We = W + (size_t)e * R * S;
  const int NT = S >> 6, NK = R >> 6;
  char* outT = (char*)WT + (((size_t)e * NT + yI) * NK + xI) * 8192;
  const int lr = tid >> 4, lc4 = tid & 15;

  #pragma unroll
  for (int j = 0; j < 4; ++j) {
    int r = lr + j * 16;
    float4 v = *(const float4*)(We + (size_t)(r0 + r) * S + s0 + lc4 * 4);
    t[r][lc4 * 4 + 0] = v.x; t[r][lc4 * 4 + 1] = v.y;
    t[r][lc4 * 4 + 2] = v.z; t[r][lc4 * 4 + 3] = v.w;
  }
  __syncthreads();
  #pragma unroll
  for (int j = 0; j < 4; ++j) {
    int sI = lr + j * 16;
    bf16x4 o;
    #pragma unroll
    for (int q = 0; q < 4; ++q) o[q] = (bf16)t[lc4 * 4 + q][sI];
    *(bf16x4*)(outT + sI * 128 + ((lc4 * 8) ^ ((sI & 7) << 4))) = o;
  }
}

// ---------------------------------------------------------------------------
// Merged: blocks [0,256) run the router (32 tokens each, wave-per-token);
// blocks [256, 256+4608) transpose W1 -> w1tT. Disjoint data, independent.
// ---------------------------------------------------------------------------
__global__ __launch_bounds__(256) void router_t1(
    const float* __restrict__ x, const float* __restrict__ Wr,
    float* __restrict__ tprob, int* __restrict__ be_out,
    int* __restrict__ cnt_blk, float* __restrict__ imp_blk,
    const float* __restrict__ W1, bf16* __restrict__ w1tT)
{
  __shared__ float smem_t[64][65];
  const int tid = threadIdx.x, lane = tid & 63, wv = tid >> 6;

  if (blockIdx.x >= NBLK) {
    const int tb = blockIdx.x - NBLK;
    const int xI = tb % 12, yI = (tb / 12) % 48, e = tb / 576;
    transpose_body(W1, w1tT, CDIM, HDIM, xI, yI, e, tid, smem_t);
    return;
  }

  // ---- router branch
  int* cnt_l = (int*)&smem_t[0][0];          // 8 ints
  float (*imp_l)[NEXP] = (float(*)[NEXP])&smem_t[1][0];
  const int b = blockIdx.x;
  if (tid < NEXP) cnt_l[tid] = 0;

  float wreg[12][8];
  #pragma unroll
  for (int j = 0; j < 3; ++j)
    #pragma unroll
    for (int q = 0; q < 4; ++q) {
      const float4* p = (const float4*)(Wr + (size_t)(j * 256 + lane * 4 + q) * 8);
      float4 lo = p[0], hi = p[1];
      wreg[j*4+q][0] = lo.x; wreg[j*4+q][1] = lo.y;
      wreg[j*4+q][2] = lo.z; wreg[j*4+q][3] = lo.w;
      wreg[j*4+q][4] = hi.x; wreg[j*4+q][5] = hi.y;
      wreg[j*4+q][6] = hi.z; wreg[j*4+q][7] = hi.w;
    }

  float impacc[NEXP];
  #pragma unroll
  for (int e = 0; e < NEXP; ++e) impacc[e] = 0.0f;
  __syncthreads();

  #pragma unroll 1
  for (int t = 0; t < 8; ++t) {
    const int tok = b * 32 + wv * 8 + t;
    float4 xv[3];
    #pragma unroll
    for (int j = 0; j < 3; ++j)
      xv[j] = *(const float4*)(x + (size_t)tok * CDIM + j * 256 + lane * 4);

    float acc[NEXP];
    #pragma unroll
    for (int e = 0; e < NEXP; ++e) acc[e] = 0.0f;
    #pragma unroll
    for (int j = 0; j < 3; ++j) {
      const float xa[4] = {xv[j].x, xv[j].y, xv[j].z, xv[j].w};
      #pragma unroll
      for (int q = 0; q < 4; ++q)
        #pragma unroll
        for (int e = 0; e < NEXP; ++e)
          acc[e] = fmaf(xa[q], wreg[j*4+q][e], acc[e]);
    }
    #pragma unroll
    for (int e = 0; e < NEXP; ++e) {
      float v = acc[e];
      v += __shfl_xor(v, 1);  v += __shfl_xor(v, 2);  v += __shfl_xor(v, 4);
      v += __shfl_xor(v, 8);  v += __shfl_xor(v, 16); v += __shfl_xor(v, 32);
      acc[e] = v;
    }
    float m = acc[0]; int be = 0;
    #pragma unroll
    for (int e = 1; e < NEXP; ++e) if (acc[e] > m) { m = acc[e]; be = e; }
    float pr[NEXP]; float s = 0.0f;
    #pragma unroll
    for (int e = 0; e < NEXP; ++e) { pr[e] = __expf(acc[e] - m); s += pr[e]; }
    const float inv = 1.0f / s;
    #pragma unroll
    for (int e = 0; e < NEXP; ++e) impacc[e] += pr[e] * inv;
    if (lane == 0) {
      tprob[tok]  = pr[be] * inv;
      be_out[tok] = be;
      atomicAdd(&cnt_l[be], 1);
    }
  }

  if (lane == 0) {
    #pragma unroll
    for (int e = 0; e < NEXP; ++e) imp_l[wv][e] = impacc[e];
  }
  __syncthreads();
  if (tid < NEXP) {
    cnt_blk[b * NEXP + tid] = cnt_l[tid];
    imp_blk[b * NEXP + tid] =
        imp_l[0][tid] + imp_l[1][tid] + imp_l[2][tid] + imp_l[3][tid];
  }
}

// ---------------------------------------------------------------------------
// Standalone transpose (post-ffn1: W2 experts 0-3 -> w2lo).
// ---------------------------------------------------------------------------
__global__ __launch_bounds__(256) void transpose_w(
    const float* __restrict__ W, bf16* __restrict__ WT, int R, int S)
{
  __shared__ float t[64][65];
  transpose_body(W, WT, R, S, blockIdx.x, blockIdx.y, blockIdx.z,
                 threadIdx.x, t);
}

// ---------------------------------------------------------------------------
// Scan: per-expert exclusive scan over 256 blocks, 128-aligned offsets,
// counts, importance, aux loss, pad tokmap = -1. No atomics.
// ---------------------------------------------------------------------------
__global__ __launch_bounds__(256) void scan_kernel(
    const int* __restrict__ cnt_blk, const float* __restrict__ imp_blk,
    int* __restrict__ counts, int* __restrict__ off,
    int* __restrict__ base_blk, float* __restrict__ out_aux,
    int* __restrict__ tokmap)
{
  const int tid = threadIdx.x, lane = tid & 63, wv = tid >> 6;
  __shared__ int   wsum[NEXP][4];
  __shared__ float wimp[NEXP][4];
  __shared__ int   off_s[9];
  __shared__ int   cnt_s[NEXP];

  int pref[NEXP];
  #pragma unroll
  for (int e = 0; e < NEXP; ++e) {
    int v = cnt_blk[tid * NEXP + e];
    int inc = v;
    #pragma unroll
    for (int o = 1; o < 64; o <<= 1) {
      int n = __shfl_up(inc, o);
      if (lane >= o) inc += n;
    }
    if (lane == 63) wsum[e][wv] = inc;
    pref[e] = inc - v;

    float f = imp_blk[tid * NEXP + e];
    f += __shfl_xor(f, 1);  f += __shfl_xor(f, 2);  f += __shfl_xor(f, 4);
    f += __shfl_xor(f, 8);  f += __shfl_xor(f, 16); f += __shfl_xor(f, 32);
    if (lane == 0) wimp[e][wv] = f;
  }
  __syncthreads();
  if (tid == 0) {
    int o = 0; float aux = 0.0f;
    #pragma unroll
    for (int e = 0; e < NEXP; ++e) {
      int tot = wsum[e][0] + wsum[e][1] + wsum[e][2] + wsum[e][3];
      float im = wimp[e][0] + wimp[e][1] + wimp[e][2] + wimp[e][3];
      counts[e] = tot;
      cnt_s[e] = tot;
      aux += im * (float)tot;
      off_s[e] = o;
      o += (tot + 127) & ~127;
    }
    off_s[8] = o;
    out_aux[0] = (float)NEXP * aux / ((float)N_TOK * (float)N_TOK);
    for (int i = 0; i < 9; ++i) off[i] = off_s[i];
  }
  __syncthreads();
  #pragma unroll
  for (int e = 0; e < NEXP; ++e) {
    int wofs = 0;
    #pragma unroll
    for (int w = 0; w < 4; ++w) if (w < wv) wofs += wsum[e][w];
    base_blk[tid * NEXP + e] = off_s[e] + wofs + pref[e];
  }
  #pragma unroll 1
  for (int e = 0; e < NEXP; ++e) {
    int p0 = off_s[e] + cnt_s[e], p1 = off_s[e + 1];
    for (int i = p0 + tid; i < p1; i += 256) tokmap[i] = -1;
  }
}

// ---------------------------------------------------------------------------
// Gather: pack routed token rows into xgT [tile128][kc:12][128][64] swizzled.
// ---------------------------------------------------------------------------
__global__ __launch_bounds__(256) void gather2(
    const float* __restrict__ x, const float* __restrict__ tprob,
    const int* __restrict__ be, const int* __restrict__ base_blk,
    bf16* __restrict__ xgT, int* __restrict__ tokmap, float* __restrict__ tpg)
{
  const int tid = threadIdx.x, lane = tid & 63, wv = tid >> 6;
  const int b = blockIdx.x;
  __shared__ int slot_l[32];

  if (wv == 0) {
    const int t = lane;
    const int bet = (t < 32) ? be[b * 32 + t] : -1;
    int slot = -1;
    #pragma unroll
    for (int e = 0; e < NEXP; ++e) {
      unsigned long long msk = __ballot(bet == e);
      if (bet == e) {
        int rank = __popcll(msk & ((1ull << lane) - 1ull));
        slot = base_blk[b * NEXP + e] + rank;
      }
    }
    if (t < 32) {
      slot_l[t] = slot;
      const int tok = b * 32 + t;
      tokmap[slot] = tok;
      tpg[slot] = tprob[tok];
    }
  }
  __syncthreads();

  #pragma unroll 1
  for (int t8 = 0; t8 < 8; ++t8) {
    const int t = wv * 8 + t8;
    const int slot = slot_l[t];
    const int tok = b * 32 + t;
    const int tile = slot >> 7, r = slot & 127;
    #pragma unroll
    for (int j = 0; j < 3; ++j) {
      const int col = j * 256 + lane * 4;
      const int kc = col >> 6, cw = col & 63;
      float4 v = *(const float4*)(x + (size_t)tok * CDIM + col);
      bf16x4 o;
      o[0] = (bf16)v.x; o[1] = (bf16)v.y; o[2] = (bf16)v.z; o[3] = (bf16)v.w;
      char* dst = (char*)xgT + (((size_t)tile * 12 + kc) * 128 + r) * 128
                  + ((cw * 2) ^ ((r & 7) << 4));
      *(bf16x4*)dst = o;
    }
  }
}

// ---------------------------------------------------------------------------
// Grouped GEMM (round-13 proven, best measured): BM=128, BN=128, BK=64,
// 4 waves. A: LDS double-buffer (2x16 KB), global_load_lds DMA, depth-2.
// B: single buffer (16 KB) -> 48 KB LDS -> 3 blocks/CU at (256,3).
// Weight base is split per expert half: e<4 -> WtLo, e>=4 -> WtHi (both
// with stride EXP_WSTRIDE). For GELU=true, grid blocks >= 1728 instead
// transpose W2 experts 4-7 into w2hi (overlapped with ffn1 compute).
// ---------------------------------------------------------------------------
template<int NKC, int NCHN, bool GELU>
__global__ __launch_bounds__(256, 3) void ffn_p(
    const bf16* __restrict__ Abuf, const bf16* __restrict__ WtLo,
    const bf16* __restrict__ WtHi,
    const float* __restrict__ bias, const int* __restrict__ off,
    const int* __restrict__ tokmap, const float* __restrict__ tpg,
    bf16* __restrict__ hbufT, float* __restrict__ y,
    const float* __restrict__ W2hiSrc, bf16* __restrict__ w2hiDst)
{
  __shared__ __attribute__((aligned(1024))) char smem[49152];
  const int tid = threadIdx.x, lane = tid & 63, wv = tid >> 6;

  const int bid = blockIdx.x;
  if (GELU && bid >= 1728) {
    // merged W2 transpose, experts 4-7 -> w2hi (disjoint from ffn1's reads)
    const int tb = bid - 1728;
    const int e4 = tb / 576, rem = tb % 576;
    const int xI = rem % 48, yI = rem / 48;       // R=HDIM tiles x S=CDIM tiles
    transpose_body(W2hiSrc, w2hiDst, HDIM, CDIM, xI, yI, e4, tid,
                   (float(*)[65])smem);
    return;
  }

  const int c  = bid & 7;
  const int r2 = bid >> 3;
  const int bx = c * 9 + (r2 % 9);
  const int by = r2 / 9;

  const int ptot = off[8];
  const int m0 = bx * 128;
  if (m0 >= ptot) return;
  int e = 0;
  #pragma unroll
  for (int q = 0; q < 7; ++q) if (m0 >= off[q + 1]) e = q + 1;

  const int wr = (wv >> 1) * 64;
  const int wc = (wv & 1) * 64;

  // A buf0 @0 (16K), A buf1 @16K, B @32K (16K)
  const char* aBase = (const char*)Abuf + (size_t)bx * NKC * 16384;
  const char* eb = (e < 4)
      ? (const char*)WtLo + (size_t)e * EXP_WSTRIDE
      : (const char*)WtHi + (size_t)(e - 4) * EXP_WSTRIDE;
  const char* bBase = eb +
      ((size_t)(by * 2 + (wv >> 1)) * NKC) * 8192 + (wv & 1) * 4096;

  auto stageA = [&](int buf, int kc) {
    const char* aS = aBase + (size_t)kc * 16384 + wv * 4096 + lane * 16;
    char* ab = smem + buf * 16384;
    #pragma unroll
    for (int i = 0; i < 4; ++i)
      load16_lds(aS + i * 1024, ab + wv * 4096 + i * 1024);
  };
  auto stageB = [&](int kc) {
    const char* bS = bBase + (size_t)kc * 8192 + lane * 16;
    char* bb = smem + 32768;
    #pragma unroll
    for (int i = 0; i < 4; ++i)
      load16_lds(bS + i * 1024, bb + wv * 4096 + i * 1024);
  };

  // hoisted swizzled byte offsets (lane-constant across the K-loop)
  int aoff[2][4], boff[2][4];
  #pragma unroll
  for (int kk = 0; kk < 2; ++kk)
    #pragma unroll
    for (int f = 0; f < 4; ++f) {
      int rowA = wr + f * 16 + (lane & 15);
      int ba   = rowA * 128 + kk * 64 + (lane >> 4) * 16;
      aoff[kk][f] = ba ^ ((rowA & 7) << 4);
      int rowB = wc + f * 16 + (lane & 15);
      int bb   = rowB * 128 + kk * 64 + (lane >> 4) * 16;
      boff[kk][f] = bb ^ ((rowB & 7) << 4);
    }

  f32x4 acc[4][4];
  #pragma unroll
  for (int i = 0; i < 4; ++i)
    #pragma unroll
    for (int j = 0; j < 4; ++j)
      #pragma unroll
      for (int q = 0; q < 4; ++q) acc[i][j][q] = 0.0f;

  // prologue: A0, B0, A1 issued; vmcnt(4) leaves A1's 4 loads in flight
  stageA(0, 0);
  stageB(0);
  stageA(1, 1);
  asm volatile("s_waitcnt vmcnt(4)" ::: "memory");

  for (int kc = 0; kc < NKC; ++kc) {
    const int cur = kc & 1;
    __builtin_amdgcn_s_barrier();          // A(cur) and B(kc) resident
    const char* A = smem + cur * 16384;
    const char* B = smem + 32768;
    bf16x8 af[2][4], bfr[2][4];
    #pragma unroll
    for (int kk = 0; kk < 2; ++kk) {
      #pragma unroll
      for (int f = 0; f < 4; ++f) af[kk][f]  = *(const bf16x8*)(A + aoff[kk][f]);
      #pragma unroll
      for (int f = 0; f < 4; ++f) bfr[kk][f] = *(const bf16x8*)(B + boff[kk][f]);
    }
    asm volatile("s_waitcnt lgkmcnt(0)" ::: "memory");
    __builtin_amdgcn_sched_barrier(0);     // rule #18: pin reads before barrier
    __builtin_amdgcn_s_barrier();          // all waves done reading A(cur), B
    if (kc + 1 < NKC) stageB(kc + 1);      // B first (drained by vmcnt(4))
    if (kc + 2 < NKC) stageA(cur, kc + 2); // A last (newest 4, stays in flight)

    __builtin_amdgcn_s_setprio(1);
    #pragma unroll
    for (int fm = 0; fm < 4; ++fm)
      #pragma unroll
      for (int fn = 0; fn < 4; ++fn)
        acc[fm][fn] = __builtin_amdgcn_mfma_f32_16x16x32_bf16(
            af[0][fm], bfr[0][fn], acc[fm][fn], 0, 0, 0);
    __builtin_amdgcn_s_setprio(0);

    if (kc + 1 < NKC) {
      __builtin_amdgcn_sched_barrier(0);
      if (kc + 2 < NKC)
        asm volatile("s_waitcnt vmcnt(4)" ::: "memory");  // A(k+2) flies
      else
        asm volatile("s_waitcnt vmcnt(0)" ::: "memory");  // tail drain
      __builtin_amdgcn_sched_barrier(0);
    }

    __builtin_amdgcn_s_setprio(1);
    #pragma unroll
    for (int fm = 0; fm < 4; ++fm)
      #pragma unroll
      for (int fn = 0; fn < 4; ++fn)
        acc[fm][fn] = __builtin_amdgcn_mfma_f32_16x16x32_bf16(
            af[1][fm], bfr[1][fn], acc[fm][fn], 0, 0, 0);
    __builtin_amdgcn_s_setprio(0);
  }
  __syncthreads();     // epilogue reuses smem

  const int g = lane >> 4, ci = lane & 15;
  float bv[4];
  #pragma unroll
  for (int fn = 0; fn < 4; ++fn)
    bv[fn] = bias[e * (NCHN * 64) + by * 128 + wc + fn * 16 + ci];

  if constexpr (GELU) {
    // bias + tanh-GELU -> swizzled bf16 C tile (32 KB) -> linear copy to hbufT
    #pragma unroll
    for (int fm = 0; fm < 4; ++fm)
      #pragma unroll
      for (int fn = 0; fn < 4; ++fn)
        #pragma unroll
        for (int rg = 0; rg < 4; ++rg) {
          int row = wr + fm * 16 + g * 4 + rg;
          int col = wc + fn * 16 + ci;
          float v = acc[fm][fn][rg] + bv[fn];
          float t3 = v + 0.044715f * v * v * v;
          float gel = v / (1.0f + __expf(-1.5957691216f * t3));
          int chunk = col >> 6, cw = col & 63;
          int byte = chunk * 16384 + row * 128 + ((cw * 2) ^ ((row & 7) << 4));
          *(bf16*)(smem + byte) = (bf16)gel;
        }
    __syncthreads();
    char* hdst = (char*)hbufT + ((size_t)bx * 48 + by * 2) * 16384;
    #pragma unroll
    for (int i = 0; i < 8; ++i) {
      int bo = (i * 256 + tid) * 16;
      *(f32x4*)(hdst + bo) = *(const f32x4*)(smem + bo);
    }
  } else {
    // bias + tprob -> two [128][68]-f32 col-halves (34 KB each) -> scatter
    float tp[4][4];
    #pragma unroll
    for (int fm = 0; fm < 4; ++fm)
      #pragma unroll
      for (int rg = 0; rg < 4; ++rg)
        tp[fm][rg] = tpg[m0 + wr + fm * 16 + g * 4 + rg];
    float* smemf = (float*)smem;
    #pragma unroll
    for (int h = 0; h < 2; ++h) {
      if ((wv & 1) == h) {
        #pragma unroll
        for (int fm = 0; fm < 4; ++fm)
          #pragma unroll
          for (int fn = 0; fn < 4; ++fn)
            #pragma unroll
            for (int rg = 0; rg < 4; ++rg) {
              int row = wr + fm * 16 + g * 4 + rg;
              int cl  = fn * 16 + ci;                // 0..63 within half
              smemf[row * 68 + cl] = (acc[fm][fn][rg] + bv[fn]) * tp[fm][rg];
            }
      }
      __syncthreads();
      // full half: 128 rows x 16 f32x4 = 2048 vec4s, 8 per thread
      #pragma unroll
      for (int it = 0; it < 8; ++it) {
        int lin = it * 256 + tid;
        int row = lin >> 4;
        int c4  = lin & 15;
        int tokr = tokmap[m0 + row];
        f32x4 v = *(const f32x4*)(smemf + row * 68 + c4 * 4);
        if (tokr >= 0)
          *(f32x4*)(y + (size_t)tokr * CDIM + by * 128 + h * 64 + c4 * 4) = v;
      }
      __syncthreads();
    }
  }
}

// ---------------------------------------------------------------------------
extern "C" void kernel_launch(void* const* d_in, const int* in_sizes, int n_in,
                              void* d_out, int out_size, void* d_ws, size_t ws_size,
                              hipStream_t stream)
{
  const float* x  = (const float*)d_in[0];
  const float* Wr = (const float*)d_in[1];
  const float* W1 = (const float*)d_in[2];
  const float* b1 = (const float*)d_in[3];
  const float* W2 = (const float*)d_in[4];
  const float* b2 = (const float*)d_in[5];
  float* out = (float*)d_out;

  char* ws = (char*)d_ws;
  int*   be         = (int*)(ws + WS_BE);
  float* tprob      = (float*)(ws + WS_TPROB);
  int*   cnt_blk    = (int*)(ws + WS_CNTB);
  float* imp_blk    = (float*)(ws + WS_IMPB);
  int*   base_blk   = (int*)(ws + WS_BASEB);
  int*   counts     = (int*)(ws + WS_CNT);
  int*   off        = (int*)(ws + WS_OFF);
  int*   tokmap     = (int*)(ws + WS_TOKMAP);
  float* tpg        = (float*)(ws + WS_TPG);
  bf16*  xgT        = (bf16*)(ws + WS_XGT);
  bf16*  w1tT       = (bf16*)(ws + WS_W1T);
  bf16*  hbufT      = (bf16*)(ws + WS_HBUF);
  bf16*  w2lo       = (bf16*)(ws + WS_W2LO);   // experts 0-3, after ffn1
  bf16*  w2hi       = (bf16*)(ws + WS_W2HI);   // experts 4-7, during ffn1

  (void)counts;

  // router (256 blocks) + W1 transpose (4608 blocks) merged
  router_t1<<<dim3(NBLK + 4608), 256, 0, stream>>>(
      x, Wr, tprob, be, cnt_blk, imp_blk, W1, w1tT);
  scan_kernel<<<dim3(1), 256, 0, stream>>>(cnt_blk, imp_blk, counts, off,
                                           base_blk, out + (size_t)N_TOK * CDIM,
                                           tokmap);
  gather2<<<dim3(NBLK), 256, 0, stream>>>(x, tprob, be, base_blk,
                                          xgT, tokmap, tpg);
  // ffn1 (1728 blocks) + W2 transpose experts 4-7 (2304 blocks) merged.
  // w1tT is contiguous for 8 experts: hi half = w1tT + 4 experts.
  ffn_p<12, 48, true><<<dim3(1728 + 2304), 256, 0, stream>>>(
      xgT, w1tT, (bf16*)((char*)w1tT + 4 * (size_t)EXP_WSTRIDE),
      b1, off, nullptr, nullptr, hbufT, nullptr,
      W2 + (size_t)4 * HDIM * CDIM, w2hi);
  // remaining W2 transpose: experts 0-3 -> w2lo (w1t region, now dead)
  transpose_w<<<dim3(HDIM / 64, CDIM / 64, 4), 256, 0, stream>>>(
      W2, w2lo, HDIM, CDIM);
  ffn_p<48, 12, false><<<dim3(432), 256, 0, stream>>>(
      hbufT, w2lo, w2hi, b2, off, tokmap, tpg, nullptr, out,
      nullptr, nullptr);
}